// Round 6
// baseline (1786.285 us; speedup 1.0000x reference)
//
#include <hip/hip_runtime.h>

// SparseLinear: out[NR,128] = segment_sum(vals[i] * W[cols[i],:], rows[i]) + b
// R5: fuse fine_sort+compute. Coarse buckets = 128 rows (row>>7).
//   coarse_hist -> coarse_scan -> partition (by row>>7) ->
//   fused_compute: per-bucket 64KB LDS out-tile, readlane broadcast + 4-wide
//   W gathers, LDS fp32 atomic accumulate (fire-and-forget), coalesced writeback.

#define UNITS 128
#define SCAN_BLK 1024
#define CH 4096          // partition chunk per block
#define NBC_SLOTS 1024   // padded coarse-bucket count (actual ~782)

// ---------- coarse histogram + scan ----------

__global__ __launch_bounds__(512) void coarse_hist_kernel(
        const int* __restrict__ rows, int* __restrict__ ccount, int nnz, int nbc) {
    __shared__ int h[NBC_SLOTS];
    int t = threadIdx.x;
    h[t] = 0; h[t + 512] = 0;
    __syncthreads();
    int stride = gridDim.x * blockDim.x;
    for (int i = blockIdx.x * blockDim.x + t; i < nnz; i += stride)
        atomicAdd(&h[rows[i] >> 7], 1);
    __syncthreads();
    int c0 = h[t], c1 = h[t + 512];
    if (c0 && t < nbc) atomicAdd(&ccount[t], c0);
    if (c1 && t + 512 < nbc) atomicAdd(&ccount[t + 512], c1);
}

__global__ __launch_bounds__(NBC_SLOTS) void coarse_scan_kernel(
        const int* __restrict__ ccount, int* __restrict__ cstart,
        int* __restrict__ ccur, int nbc) {
    __shared__ int s[NBC_SLOTS];
    int t = threadIdx.x;            // 1024 threads
    int x = (t < nbc) ? ccount[t] : 0;
    s[t] = x;
    __syncthreads();
    for (int off = 1; off < NBC_SLOTS; off <<= 1) {
        int v = (t >= off) ? s[t - off] : 0;
        __syncthreads();
        s[t] += v;
        __syncthreads();
    }
    int excl = s[t] - x;
    if (t <= nbc) cstart[t] = excl;          // cstart[nbc] = total nnz (t==nbc: excl==total)
    if (t < nbc) ccur[t] = excl;
}

// ---------- phase A: LDS-staged partition by row>>7 ----------

__global__ __launch_bounds__(512) void partition_kernel(
        const float* __restrict__ vals, const int* __restrict__ rows,
        const int* __restrict__ cols, int* __restrict__ ccur,
        float2* __restrict__ sortedA, int nnz, int nbc) {
    __shared__ float2 staged[CH];              // 32 KB: (val, packed(col|rowlo<<13))
    __shared__ unsigned short bktid[CH];       //  8 KB
    __shared__ unsigned short invs[CH];        //  8 KB
    __shared__ int hist[NBC_SLOTS];            //  4 KB (reused as rank cursor)
    __shared__ int pref[NBC_SLOTS];            //  4 KB
    __shared__ int gdelta[NBC_SLOTS];          //  4 KB

    const int t = threadIdx.x;                 // 512 threads
    const int chunk0 = blockIdx.x * CH;
    int n = nnz - chunk0;
    if (n > CH) n = CH;

    hist[t] = 0; hist[t + 512] = 0;
    __syncthreads();

    for (int r = t; r < n; r += 512) {
        int i = chunk0 + r;
        int row = rows[i];
        int col = cols[i];
        float v = vals[i];
        int b = row >> 7;
        staged[r] = make_float2(v, __int_as_float(col | ((row & 127) << 13)));
        bktid[r] = (unsigned short)b;
        atomicAdd(&hist[b], 1);
    }
    __syncthreads();

    const int b0 = t, b1 = t + 512;
    pref[b0] = hist[b0]; pref[b1] = hist[b1];
    __syncthreads();
    for (int off = 1; off < NBC_SLOTS; off <<= 1) {
        int a0 = (b0 >= off) ? pref[b0 - off] : 0;
        int a1 = (b1 >= off) ? pref[b1 - off] : 0;
        __syncthreads();
        pref[b0] += a0; pref[b1] += a1;
        __syncthreads();
    }

    int c0 = hist[b0], c1 = hist[b1];
    int ex0 = pref[b0] - c0, ex1 = pref[b1] - c1;
    if (b0 < nbc) {
        int g = (c0 > 0) ? atomicAdd(&ccur[b0], c0) : 0;
        gdelta[b0] = g - ex0;
    }
    if (b1 < nbc) {
        int g = (c1 > 0) ? atomicAdd(&ccur[b1], c1) : 0;
        gdelta[b1] = g - ex1;
    }
    __syncthreads();
    hist[b0] = ex0; hist[b1] = ex1;
    __syncthreads();

    for (int r = t; r < n; r += 512) {
        int pos = atomicAdd(&hist[bktid[r]], 1);
        invs[pos] = (unsigned short)r;
    }
    __syncthreads();

    for (int s = t; s < n; s += 512) {
        int i = invs[s];
        float2 e = staged[i];
        int b = bktid[i];
        sortedA[gdelta[b] + s] = e;
    }
}

// ---------- phase B (fused): bucket tile accumulate + bias + writeback ----------

__global__ __launch_bounds__(512) void fused_compute_kernel(
        const float2* __restrict__ A, const int* __restrict__ cstart,
        const float* __restrict__ W, const float* __restrict__ b,
        float* __restrict__ out, int NR) {
    // 128 rows x [64 X-plane | 64 Y-plane] floats; lane stride 4B -> conflict-free
    __shared__ float tile[128 * 128];          // 64 KB
    const int t = threadIdx.x;                 // 512 threads = 8 waves
    const int lane = t & 63;
    const int w = t >> 6;
    const int bb = blockIdx.x;
    const int r0 = bb << 7;

    for (int i = t; i < 128 * 128; i += 512) tile[i] = 0.f;
    __syncthreads();

    const int gstart = cstart[bb];
    const int gend   = cstart[bb + 1];
    const float2* W2 = (const float2*)W;

    for (int base = gstart + (w << 6); base < gend; base += 512) {
        int m = gend - base;
        if (m > 64) m = 64;
        float2 p = make_float2(0.f, __int_as_float(0));
        if (lane < m) p = A[base + lane];        // coalesced chunk load
        int vi = __float_as_int(p.x);
        int ci = __float_as_int(p.y);
        int rounds = (m + 3) & ~3;               // zero-pad: v=0,col=0,row=0 harmless
        for (int j = 0; j < rounds; j += 4) {
            float v0 = __int_as_float(__builtin_amdgcn_readlane(vi, j));
            int  pk0 = __builtin_amdgcn_readlane(ci, j);
            float v1 = __int_as_float(__builtin_amdgcn_readlane(vi, j + 1));
            int  pk1 = __builtin_amdgcn_readlane(ci, j + 1);
            float v2 = __int_as_float(__builtin_amdgcn_readlane(vi, j + 2));
            int  pk2 = __builtin_amdgcn_readlane(ci, j + 2);
            float v3 = __int_as_float(__builtin_amdgcn_readlane(vi, j + 3));
            int  pk3 = __builtin_amdgcn_readlane(ci, j + 3);
            int c0 = pk0 & 8191, rl0 = (pk0 >> 13) & 127;
            int c1 = pk1 & 8191, rl1 = (pk1 >> 13) & 127;
            int c2 = pk2 & 8191, rl2 = (pk2 >> 13) & 127;
            int c3 = pk3 & 8191, rl3 = (pk3 >> 13) & 127;
            float2 w0 = W2[c0 * 64 + lane];      // 4 independent L2 gathers
            float2 w1 = W2[c1 * 64 + lane];
            float2 w2 = W2[c2 * 64 + lane];
            float2 w3 = W2[c3 * 64 + lane];
            // LDS atomic accumulate: fire-and-forget, no latency chain
            atomicAdd(&tile[rl0 * 128 + lane],      v0 * w0.x);
            atomicAdd(&tile[rl0 * 128 + 64 + lane], v0 * w0.y);
            atomicAdd(&tile[rl1 * 128 + lane],      v1 * w1.x);
            atomicAdd(&tile[rl1 * 128 + 64 + lane], v1 * w1.y);
            atomicAdd(&tile[rl2 * 128 + lane],      v2 * w2.x);
            atomicAdd(&tile[rl2 * 128 + 64 + lane], v2 * w2.y);
            atomicAdd(&tile[rl3 * 128 + lane],      v3 * w3.x);
            atomicAdd(&tile[rl3 * 128 + 64 + lane], v3 * w3.y);
        }
    }
    __syncthreads();

    // writeback: 8 waves x 16 rows, coalesced float2 + bias
    float2 bb2 = ((const float2*)b)[lane];
    for (int r = w; r < 128; r += 8) {
        int grow = r0 + r;
        if (grow < NR)
            ((float2*)out)[(size_t)grow * 64 + lane] =
                make_float2(tile[r * 128 + lane] + bb2.x,
                            tile[r * 128 + 64 + lane] + bb2.y);
    }
}

// ---------- tier-2 fallback kernels (R2 pipeline) ----------

__global__ void hist_kernel(const int* __restrict__ rows, int* __restrict__ counts, int nnz) {
    int i = blockIdx.x * blockDim.x + threadIdx.x;
    if (i < nnz) atomicAdd(&counts[rows[i]], 1);
}

__global__ void scan1_kernel(const int* __restrict__ counts, int* __restrict__ tmp,
                             int* __restrict__ bsums, int NR, int NS) {
    __shared__ int s[SCAN_BLK];
    int t = threadIdx.x;
    int i = blockIdx.x * SCAN_BLK + t;
    int x = (i < NR) ? counts[i] : 0;
    s[t] = x;
    __syncthreads();
    for (int off = 1; off < SCAN_BLK; off <<= 1) {
        int v = (t >= off) ? s[t - off] : 0;
        __syncthreads();
        s[t] += v;
        __syncthreads();
    }
    if (i < NS) tmp[i] = s[t] - x;
    if (t == SCAN_BLK - 1) bsums[blockIdx.x] = s[SCAN_BLK - 1];
}

__global__ void scan2_kernel(int* __restrict__ bsums, int nb) {
    if (threadIdx.x == 0 && blockIdx.x == 0) {
        int run = 0;
        for (int i = 0; i < nb; ++i) { int c = bsums[i]; bsums[i] = run; run += c; }
    }
}

__global__ void scan3_kernel(const int* __restrict__ tmp, const int* __restrict__ bsums,
                             int* __restrict__ row_start, int* __restrict__ cursor,
                             int NR, int NS) {
    int i = blockIdx.x * blockDim.x + threadIdx.x;
    if (i < NS) {
        int v = tmp[i] + bsums[i >> 10];
        row_start[i] = v;
        if (i < NR) cursor[i] = v;
    }
}

__global__ void scatter_sort_kernel(const float* __restrict__ vals, const int* __restrict__ rows,
                                    const int* __restrict__ cols, int* __restrict__ cursor,
                                    float2* __restrict__ sorted, int nnz) {
    int i = blockIdx.x * blockDim.x + threadIdx.x;
    if (i < nnz) {
        int r = rows[i];
        int p = atomicAdd(&cursor[r], 1);
        sorted[p] = make_float2(vals[i], __int_as_float(cols[i]));
    }
}

__global__ void compute_kernel(const float2* __restrict__ sorted, const int* __restrict__ row_start,
                               const float* __restrict__ W, const float* __restrict__ b,
                               float* __restrict__ out, int NR) {
    int lane = threadIdx.x & 63;
    int wv = threadIdx.x >> 6;
    int row = blockIdx.x * 4 + wv;
    if (row >= NR) return;
    int start = row_start[row];
    int end   = row_start[row + 1];
    const float2* W2 = (const float2*)W;
    float accx0 = 0.f, accy0 = 0.f, accx1 = 0.f, accy1 = 0.f;
    for (int base = start; base < end; base += 64) {
        int m = end - base;
        if (m > 64) m = 64;
        float2 p = make_float2(0.f, __int_as_float(0));
        if (lane < m) p = sorted[base + lane];
        int vi = __float_as_int(p.x);
        int ci = __float_as_int(p.y);
        int rounds = (m + 3) & ~3;
        for (int j = 0; j < rounds; j += 4) {
            float v0 = __int_as_float(__builtin_amdgcn_readlane(vi, j));
            int   c0 = __builtin_amdgcn_readlane(ci, j);
            float v1 = __int_as_float(__builtin_amdgcn_readlane(vi, j + 1));
            int   c1 = __builtin_amdgcn_readlane(ci, j + 1);
            float v2 = __int_as_float(__builtin_amdgcn_readlane(vi, j + 2));
            int   c2 = __builtin_amdgcn_readlane(ci, j + 2);
            float v3 = __int_as_float(__builtin_amdgcn_readlane(vi, j + 3));
            int   c3 = __builtin_amdgcn_readlane(ci, j + 3);
            float2 w0 = W2[c0 * 64 + lane];
            float2 w1 = W2[c1 * 64 + lane];
            float2 w2 = W2[c2 * 64 + lane];
            float2 w3 = W2[c3 * 64 + lane];
            accx0 += v0 * w0.x; accy0 += v0 * w0.y;
            accx1 += v1 * w1.x; accy1 += v1 * w1.y;
            accx0 += v2 * w2.x; accy0 += v2 * w2.y;
            accx1 += v3 * w3.x; accy1 += v3 * w3.y;
        }
    }
    float2 bb = ((const float2*)b)[lane];
    ((float2*)out)[(size_t)row * 64 + lane] =
        make_float2(accx0 + accx1 + bb.x, accy0 + accy1 + bb.y);
}

// ---------- tier-3 fallback (atomic path) ----------

__global__ void init_bias_kernel(float* __restrict__ out, const float* __restrict__ b, int total4) {
    const float4* b4 = (const float4*)b;
    float4* out4 = (float4*)out;
    int stride = gridDim.x * blockDim.x;
    for (int j = blockIdx.x * blockDim.x + threadIdx.x; j < total4; j += stride)
        out4[j] = b4[j & 31];
}

__global__ void scatter_atomic_kernel(const float* __restrict__ vals, const int* __restrict__ rows,
                                      const int* __restrict__ cols, const float* __restrict__ W,
                                      float* __restrict__ out, int nnz) {
    long long idx = (long long)blockIdx.x * blockDim.x + threadIdx.x;
    int i = (int)(idx >> 5);
    int c = (int)(idx & 31);
    if (i >= nnz) return;
    int row = rows[i], col = cols[i];
    float v = vals[i];
    float4 w = ((const float4*)W)[col * 32 + c];
    float* o = out + (size_t)row * UNITS + (c << 2);
    atomicAdd(o + 0, v * w.x);
    atomicAdd(o + 1, v * w.y);
    atomicAdd(o + 2, v * w.z);
    atomicAdd(o + 3, v * w.w);
}

extern "C" void kernel_launch(void* const* d_in, const int* in_sizes, int n_in,
                              void* d_out, int out_size, void* d_ws, size_t ws_size,
                              hipStream_t stream) {
    const float* vals = (const float*)d_in[0];
    const int*   rows = (const int*)d_in[1];
    const int*   cols = (const int*)d_in[2];
    const float* W    = (const float*)d_in[3];
    const float* b    = (const float*)d_in[4];
    float* out = (float*)d_out;

    const int nnz = in_sizes[0];
    const int NR  = out_size / UNITS;
    const int NS  = NR + 1;
    const int NB  = (NS + SCAN_BLK - 1) / SCAN_BLK;
    const int nbc = (NR + 127) >> 7;        // 128-row coarse buckets

    auto align = [](size_t x) { return (x + 255) & ~(size_t)255; };

    // fast-path layout
    size_t off_ccount   = 0;
    size_t off_cstart   = align(off_ccount + (size_t)nbc * 4);
    size_t off_ccur     = align(off_cstart + (size_t)(nbc + 1) * 4);
    size_t off_sortedA  = align(off_ccur   + (size_t)nbc * 4);
    size_t needed_full  = off_sortedA + (size_t)nnz * 8;   // ~16 MB

    // tier-2 layout (R2 pipeline)
    size_t t2_counts   = 0;
    size_t t2_tmp      = align(t2_counts + (size_t)NR * 4);
    size_t t2_bsums    = align(t2_tmp    + (size_t)NS * 4);
    size_t t2_rowstart = align(t2_bsums  + (size_t)NB * 4);
    size_t t2_cursor   = align(t2_rowstart + (size_t)NS * 4);
    size_t t2_sorted   = align(t2_cursor + (size_t)NR * 4);
    size_t needed_r2   = t2_sorted + (size_t)nnz * 8;      // ~18 MB

    char* ws = (char*)d_ws;

    if (ws_size >= needed_full) {
        int*    ccount    = (int*)(ws + off_ccount);
        int*    cstart    = (int*)(ws + off_cstart);
        int*    ccur      = (int*)(ws + off_ccur);
        float2* sortedA   = (float2*)(ws + off_sortedA);

        hipMemsetAsync(ccount, 0, (size_t)nbc * 4, stream);
        coarse_hist_kernel<<<512, 512, 0, stream>>>(rows, ccount, nnz, nbc);
        coarse_scan_kernel<<<1, NBC_SLOTS, 0, stream>>>(ccount, cstart, ccur, nbc);
        {
            int grid = (nnz + CH - 1) / CH;
            partition_kernel<<<grid, 512, 0, stream>>>(vals, rows, cols, ccur, sortedA, nnz, nbc);
        }
        fused_compute_kernel<<<nbc, 512, 0, stream>>>(sortedA, cstart, W, b, out, NR);
    } else if (ws_size >= needed_r2) {
        int*    counts    = (int*)(ws + t2_counts);
        int*    tmp       = (int*)(ws + t2_tmp);
        int*    bsums     = (int*)(ws + t2_bsums);
        int*    row_start = (int*)(ws + t2_rowstart);
        int*    cursor    = (int*)(ws + t2_cursor);
        float2* sorted    = (float2*)(ws + t2_sorted);

        hipMemsetAsync(counts, 0, (size_t)NR * 4, stream);
        {
            int block = 256, grid = (nnz + block - 1) / block;
            hist_kernel<<<grid, block, 0, stream>>>(rows, counts, nnz);
        }
        scan1_kernel<<<NB, SCAN_BLK, 0, stream>>>(counts, tmp, bsums, NR, NS);
        scan2_kernel<<<1, 64, 0, stream>>>(bsums, NB);
        {
            int block = 256, grid = (NS + block - 1) / block;
            scan3_kernel<<<grid, block, 0, stream>>>(tmp, bsums, row_start, cursor, NR, NS);
        }
        {
            int block = 256, grid = (nnz + block - 1) / block;
            scatter_sort_kernel<<<grid, block, 0, stream>>>(vals, rows, cols, cursor, sorted, nnz);
        }
        {
            int grid = (NR + 3) / 4;
            compute_kernel<<<grid, 256, 0, stream>>>(sorted, row_start, W, b, out, NR);
        }
    } else {
        int total4 = out_size / 4;
        int block = 256;
        int grid = (total4 + block - 1) / block;
        init_bias_kernel<<<grid, block, 0, stream>>>(out, b, total4);
        long long total_threads = (long long)nnz * 32;
        long long g2 = (total_threads + block - 1) / block;
        scatter_atomic_kernel<<<(int)g2, block, 0, stream>>>(vals, rows, cols, W, out, nnz);
    }
}

// Round 7
// 224.548 us; speedup vs baseline: 7.9550x; 7.9550x over previous
//
#include <hip/hip_runtime.h>

// SparseLinear: out[NR,128] = segment_sum(vals[i] * W[cols[i],:], rows[i]) + b
// R6: fuse fine_sort + compute with REGISTER accumulation (LDS fp32 atomics are
// CAS loops on gfx950 — R5 regression). Pipeline:
//   coarse_hist -> coarse_scan -> partition (row>>8, 256-row buckets) ->
//   fused_sort_compute: stage bucket in LDS, int-atomic row sort in LDS,
//   per-wave register accumulation (4-wide W-gather ILP), coalesced out+bias.

#define UNITS 128
#define SCAN_BLK 1024
#define CH 4096          // partition chunk per block
#define NBC_SLOTS 512    // padded coarse-bucket count (actual ~391)
#define FCAP 6912        // bucket LDS capacity; mean 5120, sigma ~72

// ---------- coarse histogram + scan ----------

__global__ __launch_bounds__(256) void coarse_hist_kernel(
        const int* __restrict__ rows, int* __restrict__ ccount, int nnz, int nbc) {
    __shared__ int h[NBC_SLOTS];
    int t = threadIdx.x;
    h[t] = 0; h[t + 256] = 0;
    __syncthreads();
    int stride = gridDim.x * blockDim.x;
    for (int i = blockIdx.x * blockDim.x + t; i < nnz; i += stride)
        atomicAdd(&h[rows[i] >> 8], 1);
    __syncthreads();
    int c0 = h[t], c1 = h[t + 256];
    if (c0 && t < nbc) atomicAdd(&ccount[t], c0);
    if (c1 && t + 256 < nbc) atomicAdd(&ccount[t + 256], c1);
}

__global__ __launch_bounds__(NBC_SLOTS) void coarse_scan_kernel(
        const int* __restrict__ ccount, int* __restrict__ cstart,
        int* __restrict__ ccur, int nbc) {
    __shared__ int s[NBC_SLOTS];
    int t = threadIdx.x;            // 512 threads
    int x = (t < nbc) ? ccount[t] : 0;
    s[t] = x;
    __syncthreads();
    for (int off = 1; off < NBC_SLOTS; off <<= 1) {
        int v = (t >= off) ? s[t - off] : 0;
        __syncthreads();
        s[t] += v;
        __syncthreads();
    }
    int excl = s[t] - x;
    if (t <= nbc) cstart[t] = excl;          // cstart[nbc] = total nnz
    if (t < nbc) ccur[t] = excl;
}

// ---------- phase A: LDS-staged partition by row>>8 ----------

__global__ __launch_bounds__(256) void partition_kernel(
        const float* __restrict__ vals, const int* __restrict__ rows,
        const int* __restrict__ cols, int* __restrict__ ccur,
        float2* __restrict__ sortedA, int nnz, int nbc) {
    __shared__ float2 staged[CH];              // 32 KB: (val, packed(col|rowlo<<13))
    __shared__ unsigned short bktid[CH];       //  8 KB
    __shared__ unsigned short invs[CH];        //  8 KB
    __shared__ int hist[NBC_SLOTS];            //  2 KB (reused as rank cursor)
    __shared__ int pref[NBC_SLOTS];            //  2 KB
    __shared__ int gdelta[NBC_SLOTS];          //  2 KB

    const int t = threadIdx.x;                 // 256 threads
    const int chunk0 = blockIdx.x * CH;
    int n = nnz - chunk0;
    if (n > CH) n = CH;

    hist[t] = 0; hist[t + 256] = 0;
    __syncthreads();

    for (int r = t; r < n; r += 256) {
        int i = chunk0 + r;
        int row = rows[i];
        int col = cols[i];
        float v = vals[i];
        int b = row >> 8;
        staged[r] = make_float2(v, __int_as_float(col | ((row & 255) << 13)));
        bktid[r] = (unsigned short)b;
        atomicAdd(&hist[b], 1);
    }
    __syncthreads();

    const int b0 = t, b1 = t + 256;
    pref[b0] = hist[b0]; pref[b1] = hist[b1];
    __syncthreads();
    for (int off = 1; off < NBC_SLOTS; off <<= 1) {
        int a0 = (b0 >= off) ? pref[b0 - off] : 0;
        int a1 = (b1 >= off) ? pref[b1 - off] : 0;
        __syncthreads();
        pref[b0] += a0; pref[b1] += a1;
        __syncthreads();
    }

    int c0 = hist[b0], c1 = hist[b1];
    int ex0 = pref[b0] - c0, ex1 = pref[b1] - c1;
    if (b0 < nbc) {
        int g = (c0 > 0) ? atomicAdd(&ccur[b0], c0) : 0;
        gdelta[b0] = g - ex0;
    }
    if (b1 < nbc) {
        int g = (c1 > 0) ? atomicAdd(&ccur[b1], c1) : 0;
        gdelta[b1] = g - ex1;
    }
    __syncthreads();
    hist[b0] = ex0; hist[b1] = ex1;
    __syncthreads();

    for (int r = t; r < n; r += 256) {
        int pos = atomicAdd(&hist[bktid[r]], 1);
        invs[pos] = (unsigned short)r;
    }
    __syncthreads();

    for (int s = t; s < n; s += 256) {
        int i = invs[s];
        float2 e = staged[i];
        int b = bktid[i];
        sortedA[gdelta[b] + s] = e;
    }
}

// ---------- phase B (fused): in-LDS row sort + register accumulate ----------

__global__ __launch_bounds__(1024) void fused_sort_compute_kernel(
        const float2* __restrict__ A, const int* __restrict__ cstart,
        const float* __restrict__ W, const float* __restrict__ b,
        float* __restrict__ out, int NR) {
    __shared__ float2 st[FCAP + 4];   // ~55.3 KB (sorted (val,col) pairs)
    __shared__ int cnt_s[256];        // counts -> scatter cursor
    __shared__ int rs[257];           // stable row starts (local)
    const int t = threadIdx.x;        // 1024 threads = 16 waves
    const int lane = t & 63;
    const int w = t >> 6;
    const int bb = blockIdx.x;
    const int r0 = bb << 8;
    const int gstart = cstart[bb];
    const int cnt = cstart[bb + 1] - gstart;

    const float2* W2 = (const float2*)W;
    const float2 bias = ((const float2*)b)[lane];

    if (t < 256) cnt_s[t] = 0;
    __syncthreads();

    if (cnt <= FCAP) {
        // pass 1: histogram row-lows (packed ints only)
        const int* Ai = (const int*)(A + gstart);
        for (int k = t; k < cnt; k += 1024)
            atomicAdd(&cnt_s[(Ai[2 * k + 1] >> 13) & 255], 1);
        __syncthreads();

        // exclusive scan over 256 counts (all threads hit barriers)
        if (t < 256) rs[t] = cnt_s[t];
        __syncthreads();
        for (int off = 1; off < 256; off <<= 1) {
            int v = (t < 256 && t >= off) ? rs[t - off] : 0;
            __syncthreads();
            if (t < 256) rs[t] += v;
            __syncthreads();
        }
        int excl = (t < 256) ? rs[t] - cnt_s[t] : 0;
        __syncthreads();
        if (t < 256) { rs[t] = excl; cnt_s[t] = excl; }
        if (t == 0) rs[256] = cnt;
        __syncthreads();

        // pass 2: scatter into LDS in exact row order (native int LDS atomics)
        for (int k = t; k < cnt; k += 1024) {
            float2 e = A[gstart + k];
            int pk = __float_as_int(e.y);
            int p = atomicAdd(&cnt_s[(pk >> 13) & 255], 1);
            st[p] = make_float2(e.x, __int_as_float(pk & 8191));
        }
        __syncthreads();

        // compute: wave w -> rows [w*16, w*16+16), register accumulation
        int rbeg = w << 4;
        for (int r = rbeg; r < rbeg + 16; ++r) {
            int grow = r0 + r;
            if (grow >= NR) break;
            int s = rs[r], e = rs[r + 1];
            float ax0 = 0.f, ay0 = 0.f, ax1 = 0.f, ay1 = 0.f;
            for (int k = s; k < e; k += 4) {
                // broadcast LDS reads (wave-uniform addresses); st has +4 pad
                float2 p0 = st[k];
                float2 p1 = st[k + 1];
                float2 p2 = st[k + 2];
                float2 p3 = st[k + 3];
                int c0 = __float_as_int(p0.y) & 8191;
                int c1 = __float_as_int(p1.y) & 8191;
                int c2 = __float_as_int(p2.y) & 8191;
                int c3 = __float_as_int(p3.y) & 8191;
                float v0 = p0.x;
                float v1 = (k + 1 < e) ? p1.x : 0.f;
                float v2 = (k + 2 < e) ? p2.x : 0.f;
                float v3 = (k + 3 < e) ? p3.x : 0.f;
                float2 w0 = W2[c0 * 64 + lane];   // 4 independent L2 gathers
                float2 w1 = W2[c1 * 64 + lane];
                float2 w2 = W2[c2 * 64 + lane];
                float2 w3 = W2[c3 * 64 + lane];
                ax0 += v0 * w0.x; ay0 += v0 * w0.y;
                ax1 += v1 * w1.x; ay1 += v1 * w1.y;
                ax0 += v2 * w2.x; ay0 += v2 * w2.y;
                ax1 += v3 * w3.x; ay1 += v3 * w3.y;
            }
            ((float2*)out)[(size_t)grow * 64 + lane] =
                make_float2(ax0 + ax1 + bias.x, ay0 + ay1 + bias.y);
        }
    } else {
        // overflow (>FCAP, ~25 sigma — correctness only): bias init + native
        // global fp32 atomics. Block owns its rows exclusively.
        for (int r = w; r < 256; r += 16) {
            int grow = r0 + r;
            if (grow < NR)
                ((float2*)out)[(size_t)grow * 64 + lane] = bias;
        }
        __syncthreads();
        int gend = gstart + cnt;
        for (int base = gstart + (w << 6); base < gend; base += 1024) {
            int m = gend - base;
            if (m > 64) m = 64;
            float2 p = make_float2(0.f, __int_as_float(0));
            if (lane < m) p = A[base + lane];
            int vi = __float_as_int(p.x);
            int ci = __float_as_int(p.y);
            for (int j = 0; j < m; ++j) {
                float v = __int_as_float(__builtin_amdgcn_readlane(vi, j));
                int pk = __builtin_amdgcn_readlane(ci, j);
                int c = pk & 8191, rl = (pk >> 13) & 255;
                int grow = r0 + rl;
                if (grow >= NR) continue;
                float2 wv = W2[c * 64 + lane];
                float* o = out + (size_t)grow * 128;
                atomicAdd(o + lane, v * wv.x);
                atomicAdd(o + 64 + lane, v * wv.y);
            }
        }
    }
}

// ---------- tier-2 fallback kernels (R2 pipeline) ----------

__global__ void hist_kernel(const int* __restrict__ rows, int* __restrict__ counts, int nnz) {
    int i = blockIdx.x * blockDim.x + threadIdx.x;
    if (i < nnz) atomicAdd(&counts[rows[i]], 1);
}

__global__ void scan1_kernel(const int* __restrict__ counts, int* __restrict__ tmp,
                             int* __restrict__ bsums, int NR, int NS) {
    __shared__ int s[SCAN_BLK];
    int t = threadIdx.x;
    int i = blockIdx.x * SCAN_BLK + t;
    int x = (i < NR) ? counts[i] : 0;
    s[t] = x;
    __syncthreads();
    for (int off = 1; off < SCAN_BLK; off <<= 1) {
        int v = (t >= off) ? s[t - off] : 0;
        __syncthreads();
        s[t] += v;
        __syncthreads();
    }
    if (i < NS) tmp[i] = s[t] - x;
    if (t == SCAN_BLK - 1) bsums[blockIdx.x] = s[SCAN_BLK - 1];
}

__global__ void scan2_kernel(int* __restrict__ bsums, int nb) {
    if (threadIdx.x == 0 && blockIdx.x == 0) {
        int run = 0;
        for (int i = 0; i < nb; ++i) { int c = bsums[i]; bsums[i] = run; run += c; }
    }
}

__global__ void scan3_kernel(const int* __restrict__ tmp, const int* __restrict__ bsums,
                             int* __restrict__ row_start, int* __restrict__ cursor,
                             int NR, int NS) {
    int i = blockIdx.x * blockDim.x + threadIdx.x;
    if (i < NS) {
        int v = tmp[i] + bsums[i >> 10];
        row_start[i] = v;
        if (i < NR) cursor[i] = v;
    }
}

__global__ void scatter_sort_kernel(const float* __restrict__ vals, const int* __restrict__ rows,
                                    const int* __restrict__ cols, int* __restrict__ cursor,
                                    float2* __restrict__ sorted, int nnz) {
    int i = blockIdx.x * blockDim.x + threadIdx.x;
    if (i < nnz) {
        int r = rows[i];
        int p = atomicAdd(&cursor[r], 1);
        sorted[p] = make_float2(vals[i], __int_as_float(cols[i]));
    }
}

__global__ void compute_kernel(const float2* __restrict__ sorted, const int* __restrict__ row_start,
                               const float* __restrict__ W, const float* __restrict__ b,
                               float* __restrict__ out, int NR) {
    int lane = threadIdx.x & 63;
    int wv = threadIdx.x >> 6;
    int row = blockIdx.x * 4 + wv;
    if (row >= NR) return;
    int start = row_start[row];
    int end   = row_start[row + 1];
    const float2* W2 = (const float2*)W;
    float accx0 = 0.f, accy0 = 0.f, accx1 = 0.f, accy1 = 0.f;
    for (int base = start; base < end; base += 64) {
        int m = end - base;
        if (m > 64) m = 64;
        float2 p = make_float2(0.f, __int_as_float(0));
        if (lane < m) p = sorted[base + lane];
        int vi = __float_as_int(p.x);
        int ci = __float_as_int(p.y);
        int rounds = (m + 3) & ~3;
        for (int j = 0; j < rounds; j += 4) {
            float v0 = __int_as_float(__builtin_amdgcn_readlane(vi, j));
            int   c0 = __builtin_amdgcn_readlane(ci, j);
            float v1 = __int_as_float(__builtin_amdgcn_readlane(vi, j + 1));
            int   c1 = __builtin_amdgcn_readlane(ci, j + 1);
            float v2 = __int_as_float(__builtin_amdgcn_readlane(vi, j + 2));
            int   c2 = __builtin_amdgcn_readlane(ci, j + 2);
            float v3 = __int_as_float(__builtin_amdgcn_readlane(vi, j + 3));
            int   c3 = __builtin_amdgcn_readlane(ci, j + 3);
            float2 w0 = W2[c0 * 64 + lane];
            float2 w1 = W2[c1 * 64 + lane];
            float2 w2 = W2[c2 * 64 + lane];
            float2 w3 = W2[c3 * 64 + lane];
            accx0 += v0 * w0.x; accy0 += v0 * w0.y;
            accx1 += v1 * w1.x; accy1 += v1 * w1.y;
            accx0 += v2 * w2.x; accy0 += v2 * w2.y;
            accx1 += v3 * w3.x; accy1 += v3 * w3.y;
        }
    }
    float2 bb = ((const float2*)b)[lane];
    ((float2*)out)[(size_t)row * 64 + lane] =
        make_float2(accx0 + accx1 + bb.x, accy0 + accy1 + bb.y);
}

// ---------- tier-3 fallback (atomic path) ----------

__global__ void init_bias_kernel(float* __restrict__ out, const float* __restrict__ b, int total4) {
    const float4* b4 = (const float4*)b;
    float4* out4 = (float4*)out;
    int stride = gridDim.x * blockDim.x;
    for (int j = blockIdx.x * blockDim.x + threadIdx.x; j < total4; j += stride)
        out4[j] = b4[j & 31];
}

__global__ void scatter_atomic_kernel(const float* __restrict__ vals, const int* __restrict__ rows,
                                      const int* __restrict__ cols, const float* __restrict__ W,
                                      float* __restrict__ out, int nnz) {
    long long idx = (long long)blockIdx.x * blockDim.x + threadIdx.x;
    int i = (int)(idx >> 5);
    int c = (int)(idx & 31);
    if (i >= nnz) return;
    int row = rows[i], col = cols[i];
    float v = vals[i];
    float4 w = ((const float4*)W)[col * 32 + c];
    float* o = out + (size_t)row * UNITS + (c << 2);
    atomicAdd(o + 0, v * w.x);
    atomicAdd(o + 1, v * w.y);
    atomicAdd(o + 2, v * w.z);
    atomicAdd(o + 3, v * w.w);
}

extern "C" void kernel_launch(void* const* d_in, const int* in_sizes, int n_in,
                              void* d_out, int out_size, void* d_ws, size_t ws_size,
                              hipStream_t stream) {
    const float* vals = (const float*)d_in[0];
    const int*   rows = (const int*)d_in[1];
    const int*   cols = (const int*)d_in[2];
    const float* W    = (const float*)d_in[3];
    const float* b    = (const float*)d_in[4];
    float* out = (float*)d_out;

    const int nnz = in_sizes[0];
    const int NR  = out_size / UNITS;
    const int NS  = NR + 1;
    const int NB  = (NS + SCAN_BLK - 1) / SCAN_BLK;
    const int nbc = (NR + 255) >> 8;        // 256-row coarse buckets

    auto align = [](size_t x) { return (x + 255) & ~(size_t)255; };

    // fast-path layout
    size_t off_ccount   = 0;
    size_t off_cstart   = align(off_ccount + (size_t)nbc * 4);
    size_t off_ccur     = align(off_cstart + (size_t)(nbc + 1) * 4);
    size_t off_sortedA  = align(off_ccur   + (size_t)nbc * 4);
    size_t needed_full  = off_sortedA + (size_t)nnz * 8;   // ~16 MB

    // tier-2 layout (R2 pipeline)
    size_t t2_counts   = 0;
    size_t t2_tmp      = align(t2_counts + (size_t)NR * 4);
    size_t t2_bsums    = align(t2_tmp    + (size_t)NS * 4);
    size_t t2_rowstart = align(t2_bsums  + (size_t)NB * 4);
    size_t t2_cursor   = align(t2_rowstart + (size_t)NS * 4);
    size_t t2_sorted   = align(t2_cursor + (size_t)NR * 4);
    size_t needed_r2   = t2_sorted + (size_t)nnz * 8;      // ~18 MB

    char* ws = (char*)d_ws;

    if (ws_size >= needed_full) {
        int*    ccount    = (int*)(ws + off_ccount);
        int*    cstart    = (int*)(ws + off_cstart);
        int*    ccur      = (int*)(ws + off_ccur);
        float2* sortedA   = (float2*)(ws + off_sortedA);

        hipMemsetAsync(ccount, 0, (size_t)nbc * 4, stream);
        coarse_hist_kernel<<<512, 256, 0, stream>>>(rows, ccount, nnz, nbc);
        coarse_scan_kernel<<<1, NBC_SLOTS, 0, stream>>>(ccount, cstart, ccur, nbc);
        {
            int grid = (nnz + CH - 1) / CH;
            partition_kernel<<<grid, 256, 0, stream>>>(vals, rows, cols, ccur, sortedA, nnz, nbc);
        }
        fused_sort_compute_kernel<<<nbc, 1024, 0, stream>>>(sortedA, cstart, W, b, out, NR);
    } else if (ws_size >= needed_r2) {
        int*    counts    = (int*)(ws + t2_counts);
        int*    tmp       = (int*)(ws + t2_tmp);
        int*    bsums     = (int*)(ws + t2_bsums);
        int*    row_start = (int*)(ws + t2_rowstart);
        int*    cursor    = (int*)(ws + t2_cursor);
        float2* sorted    = (float2*)(ws + t2_sorted);

        hipMemsetAsync(counts, 0, (size_t)NR * 4, stream);
        {
            int block = 256, grid = (nnz + block - 1) / block;
            hist_kernel<<<grid, block, 0, stream>>>(rows, counts, nnz);
        }
        scan1_kernel<<<NB, SCAN_BLK, 0, stream>>>(counts, tmp, bsums, NR, NS);
        scan2_kernel<<<1, 64, 0, stream>>>(bsums, NB);
        {
            int block = 256, grid = (NS + block - 1) / block;
            scan3_kernel<<<grid, block, 0, stream>>>(tmp, bsums, row_start, cursor, NR, NS);
        }
        {
            int block = 256, grid = (nnz + block - 1) / block;
            scatter_sort_kernel<<<grid, block, 0, stream>>>(vals, rows, cols, cursor, sorted, nnz);
        }
        {
            int grid = (NR + 3) / 4;
            compute_kernel<<<grid, 256, 0, stream>>>(sorted, row_start, W, b, out, NR);
        }
    } else {
        int total4 = out_size / 4;
        int block = 256;
        int grid = (total4 + block - 1) / block;
        init_bias_kernel<<<grid, block, 0, stream>>>(out, b, total4);
        long long total_threads = (long long)nnz * 32;
        long long g2 = (total_threads + block - 1) / block;
        scatter_atomic_kernel<<<(int)g2, block, 0, stream>>>(vals, rows, cols, W, out, nnz);
    }
}

// Round 8
// 173.216 us; speedup vs baseline: 10.3125x; 1.2963x over previous
//
#include <hip/hip_runtime.h>
#include <hip/hip_fp16.h>

// SparseLinear: out[NR,128] = segment_sum(vals[i] * W[cols[i],:], rows[i]) + b
// R7: (a) W gathered as fp16 (half traffic, 2MB table stays L2-resident);
//     (b) fixed-capacity buckets (kill coarse_hist/scan/memset; 3 dispatches).
//   setup: ccur[b]=b*CAP, spill_cnt=0, W->half convert
//   partition: LDS-staged partition by row>>8 into fixed bucket ranges (+spill)
//   fused: in-LDS exact row sort + per-wave register accumulation (fp16 gathers)

#define UNITS 128
#define SCAN_BLK 1024
#define CH 4096          // partition chunk per block
#define NBC_SLOTS 512    // padded coarse-bucket count (actual ~391)
#define FCAP 6912        // fused LDS capacity (entries)
#define BCAP 6656        // fixed bucket capacity (mean 5120, +21 sigma)
#define SPILL_CAP 8192

// ---------- setup: cursors + spill counter + W fp32->fp16 ----------

__global__ __launch_bounds__(256) void setup_kernel(
        const float* __restrict__ W, __half2* __restrict__ Wh,
        int* __restrict__ ccur, int* __restrict__ spill_cnt,
        int nbc, int wn2 /* = 8192*128/2 half2 elements */) {
    int t = blockIdx.x * blockDim.x + threadIdx.x;
    if (t < nbc) ccur[t] = t * BCAP;
    if (t == nbc) *spill_cnt = 0;
    int stride = gridDim.x * blockDim.x;
    const float2* W2 = (const float2*)W;
    for (int i = t; i < wn2; i += stride)
        Wh[i] = __float22half2_rn(W2[i]);
}

// ---------- phase A: LDS-staged partition by row>>8 (fixed bases) ----------

__global__ __launch_bounds__(256) void partition_kernel(
        const float* __restrict__ vals, const int* __restrict__ rows,
        const int* __restrict__ cols, int* __restrict__ ccur,
        float2* __restrict__ sortedA, int* __restrict__ spill_cnt,
        float2* __restrict__ spill, int nnz, int nbc) {
    __shared__ float2 staged[CH];              // 32 KB: (val, packed(col|rowlo<<13))
    __shared__ unsigned short bktid[CH];       //  8 KB
    __shared__ unsigned short invs[CH];        //  8 KB
    __shared__ int hist[NBC_SLOTS];            //  2 KB (reused as rank cursor)
    __shared__ int pref[NBC_SLOTS];            //  2 KB
    __shared__ int gdelta[NBC_SLOTS];          //  2 KB

    const int t = threadIdx.x;                 // 256 threads
    const int chunk0 = blockIdx.x * CH;
    int n = nnz - chunk0;
    if (n > CH) n = CH;

    hist[t] = 0; hist[t + 256] = 0;
    __syncthreads();

    for (int r = t; r < n; r += 256) {
        int i = chunk0 + r;
        int row = rows[i];
        int col = cols[i];
        float v = vals[i];
        int b = row >> 8;
        staged[r] = make_float2(v, __int_as_float(col | ((row & 255) << 13)));
        bktid[r] = (unsigned short)b;
        atomicAdd(&hist[b], 1);
    }
    __syncthreads();

    const int b0 = t, b1 = t + 256;
    pref[b0] = hist[b0]; pref[b1] = hist[b1];
    __syncthreads();
    for (int off = 1; off < NBC_SLOTS; off <<= 1) {
        int a0 = (b0 >= off) ? pref[b0 - off] : 0;
        int a1 = (b1 >= off) ? pref[b1 - off] : 0;
        __syncthreads();
        pref[b0] += a0; pref[b1] += a1;
        __syncthreads();
    }

    int c0 = hist[b0], c1 = hist[b1];
    int ex0 = pref[b0] - c0, ex1 = pref[b1] - c1;
    if (b0 < nbc) {
        int g = (c0 > 0) ? atomicAdd(&ccur[b0], c0) : 0;
        gdelta[b0] = g - ex0;
    }
    if (b1 < nbc) {
        int g = (c1 > 0) ? atomicAdd(&ccur[b1], c1) : 0;
        gdelta[b1] = g - ex1;
    }
    __syncthreads();
    hist[b0] = ex0; hist[b1] = ex1;
    __syncthreads();

    for (int r = t; r < n; r += 256) {
        int pos = atomicAdd(&hist[bktid[r]], 1);
        invs[pos] = (unsigned short)r;
    }
    __syncthreads();

    for (int s = t; s < n; s += 256) {
        int i = invs[s];
        float2 e = staged[i];
        int b = bktid[i];
        int dest = gdelta[b] + s;
        if (dest < (b + 1) * BCAP) {
            sortedA[dest] = e;                 // grouped, mostly-coalesced
        } else {
            // bucket overflow (~21 sigma): spill with full row id
            int sp = atomicAdd(spill_cnt, 1);
            if (sp < SPILL_CAP) {
                int pk = __float_as_int(e.y);
                int row = (b << 8) | ((pk >> 13) & 255);
                spill[sp] = make_float2(e.x, __int_as_float((pk & 8191) | (row << 13)));
            }
        }
    }
}

// ---------- phase B (fused): in-LDS row sort + register accumulate ----------

__global__ __launch_bounds__(1024) void fused_sort_compute_kernel(
        const float2* __restrict__ A, const int* __restrict__ ccur,
        const __half2* __restrict__ Wh, const float* __restrict__ b,
        float* __restrict__ out, const int* __restrict__ spill_cnt,
        const float2* __restrict__ spill, int NR) {
    __shared__ float2 st[FCAP + 4];   // ~55.3 KB (sorted (val,col) pairs)
    __shared__ int cnt_s[256];        // counts -> scatter cursor
    __shared__ int rs[257];           // stable local row starts
    __shared__ int spill_n;
    const int t = threadIdx.x;        // 1024 threads = 16 waves
    const int lane = t & 63;
    const int w = t >> 6;
    const int bb = blockIdx.x;
    const int r0 = bb << 8;
    const int gstart = bb * BCAP;
    int cnt = ccur[bb] - gstart;
    if (cnt > BCAP) cnt = BCAP;       // overflow entries are in the spill list

    const float2 bias = ((const float2*)b)[lane];

    if (t < 256) cnt_s[t] = 0;
    if (t == 0) {
        int sn = *spill_cnt;
        spill_n = (sn > SPILL_CAP) ? SPILL_CAP : sn;
    }
    __syncthreads();

    // pass 1: histogram row-lows (packed ints only)
    const int* Ai = (const int*)(A + gstart);
    for (int k = t; k < cnt; k += 1024)
        atomicAdd(&cnt_s[(Ai[2 * k + 1] >> 13) & 255], 1);
    __syncthreads();

    // exclusive scan over 256 counts
    if (t < 256) rs[t] = cnt_s[t];
    __syncthreads();
    for (int off = 1; off < 256; off <<= 1) {
        int v = (t < 256 && t >= off) ? rs[t - off] : 0;
        __syncthreads();
        if (t < 256) rs[t] += v;
        __syncthreads();
    }
    int excl = (t < 256) ? rs[t] - cnt_s[t] : 0;
    __syncthreads();
    if (t < 256) { rs[t] = excl; cnt_s[t] = excl; }
    if (t == 0) rs[256] = cnt;
    __syncthreads();

    // pass 2: scatter into LDS in exact row order (native int LDS atomics)
    for (int k = t; k < cnt; k += 1024) {
        float2 e = A[gstart + k];
        int pk = __float_as_int(e.y);
        int p = atomicAdd(&cnt_s[(pk >> 13) & 255], 1);
        st[p] = make_float2(e.x, __int_as_float(pk & 8191));
    }
    __syncthreads();

    // compute: wave w -> rows [w*16, w*16+16), register accumulation,
    // fp16 W gathers (L2-resident 2MB table)
    const int sn = spill_n;
    int rbeg = w << 4;
    for (int r = rbeg; r < rbeg + 16; ++r) {
        int grow = r0 + r;
        if (grow >= NR) break;
        int s = rs[r], e = rs[r + 1];
        float ax0 = 0.f, ay0 = 0.f, ax1 = 0.f, ay1 = 0.f;
        for (int k = s; k < e; k += 4) {
            float2 p0 = st[k];
            float2 p1 = st[k + 1];
            float2 p2 = st[k + 2];
            float2 p3 = st[k + 3];
            int c0 = __float_as_int(p0.y) & 8191;
            int c1 = __float_as_int(p1.y) & 8191;
            int c2 = __float_as_int(p2.y) & 8191;
            int c3 = __float_as_int(p3.y) & 8191;
            float v0 = p0.x;
            float v1 = (k + 1 < e) ? p1.x : 0.f;
            float v2 = (k + 2 < e) ? p2.x : 0.f;
            float v3 = (k + 3 < e) ? p3.x : 0.f;
            float2 w0 = __half22float2(Wh[c0 * 64 + lane]);  // 4 independent L2 gathers
            float2 w1 = __half22float2(Wh[c1 * 64 + lane]);
            float2 w2 = __half22float2(Wh[c2 * 64 + lane]);
            float2 w3 = __half22float2(Wh[c3 * 64 + lane]);
            ax0 += v0 * w0.x; ay0 += v0 * w0.y;
            ax1 += v1 * w1.x; ay1 += v1 * w1.y;
            ax0 += v2 * w2.x; ay0 += v2 * w2.y;
            ax1 += v3 * w3.x; ay1 += v3 * w3.y;
        }
        // spill entries (normally sn == 0)
        for (int s2 = 0; s2 < sn; ++s2) {
            float2 es = spill[s2];
            int pk = __float_as_int(es.y);
            if ((pk >> 13) == grow) {
                float2 wv = __half22float2(Wh[(pk & 8191) * 64 + lane]);
                ax0 += es.x * wv.x; ay0 += es.x * wv.y;
            }
        }
        ((float2*)out)[(size_t)grow * 64 + lane] =
            make_float2(ax0 + ax1 + bias.x, ay0 + ay1 + bias.y);
    }
}

// ---------- tier-2 fallback kernels (R2 pipeline, fp32 W) ----------

__global__ void hist_kernel(const int* __restrict__ rows, int* __restrict__ counts, int nnz) {
    int i = blockIdx.x * blockDim.x + threadIdx.x;
    if (i < nnz) atomicAdd(&counts[rows[i]], 1);
}

__global__ void scan1_kernel(const int* __restrict__ counts, int* __restrict__ tmp,
                             int* __restrict__ bsums, int NR, int NS) {
    __shared__ int s[SCAN_BLK];
    int t = threadIdx.x;
    int i = blockIdx.x * SCAN_BLK + t;
    int x = (i < NR) ? counts[i] : 0;
    s[t] = x;
    __syncthreads();
    for (int off = 1; off < SCAN_BLK; off <<= 1) {
        int v = (t >= off) ? s[t - off] : 0;
        __syncthreads();
        s[t] += v;
        __syncthreads();
    }
    if (i < NS) tmp[i] = s[t] - x;
    if (t == SCAN_BLK - 1) bsums[blockIdx.x] = s[SCAN_BLK - 1];
}

__global__ void scan2_kernel(int* __restrict__ bsums, int nb) {
    if (threadIdx.x == 0 && blockIdx.x == 0) {
        int run = 0;
        for (int i = 0; i < nb; ++i) { int c = bsums[i]; bsums[i] = run; run += c; }
    }
}

__global__ void scan3_kernel(const int* __restrict__ tmp, const int* __restrict__ bsums,
                             int* __restrict__ row_start, int* __restrict__ cursor,
                             int NR, int NS) {
    int i = blockIdx.x * blockDim.x + threadIdx.x;
    if (i < NS) {
        int v = tmp[i] + bsums[i >> 10];
        row_start[i] = v;
        if (i < NR) cursor[i] = v;
    }
}

__global__ void scatter_sort_kernel(const float* __restrict__ vals, const int* __restrict__ rows,
                                    const int* __restrict__ cols, int* __restrict__ cursor,
                                    float2* __restrict__ sorted, int nnz) {
    int i = blockIdx.x * blockDim.x + threadIdx.x;
    if (i < nnz) {
        int r = rows[i];
        int p = atomicAdd(&cursor[r], 1);
        sorted[p] = make_float2(vals[i], __int_as_float(cols[i]));
    }
}

__global__ void compute_kernel(const float2* __restrict__ sorted, const int* __restrict__ row_start,
                               const float* __restrict__ W, const float* __restrict__ b,
                               float* __restrict__ out, int NR) {
    int lane = threadIdx.x & 63;
    int wv = threadIdx.x >> 6;
    int row = blockIdx.x * 4 + wv;
    if (row >= NR) return;
    int start = row_start[row];
    int end   = row_start[row + 1];
    const float2* W2 = (const float2*)W;
    float accx0 = 0.f, accy0 = 0.f, accx1 = 0.f, accy1 = 0.f;
    for (int base = start; base < end; base += 64) {
        int m = end - base;
        if (m > 64) m = 64;
        float2 p = make_float2(0.f, __int_as_float(0));
        if (lane < m) p = sorted[base + lane];
        int vi = __float_as_int(p.x);
        int ci = __float_as_int(p.y);
        int rounds = (m + 3) & ~3;
        for (int j = 0; j < rounds; j += 4) {
            float v0 = __int_as_float(__builtin_amdgcn_readlane(vi, j));
            int   c0 = __builtin_amdgcn_readlane(ci, j);
            float v1 = __int_as_float(__builtin_amdgcn_readlane(vi, j + 1));
            int   c1 = __builtin_amdgcn_readlane(ci, j + 1);
            float v2 = __int_as_float(__builtin_amdgcn_readlane(vi, j + 2));
            int   c2 = __builtin_amdgcn_readlane(ci, j + 2);
            float v3 = __int_as_float(__builtin_amdgcn_readlane(vi, j + 3));
            int   c3 = __builtin_amdgcn_readlane(ci, j + 3);
            float2 w0 = W2[c0 * 64 + lane];
            float2 w1 = W2[c1 * 64 + lane];
            float2 w2 = W2[c2 * 64 + lane];
            float2 w3 = W2[c3 * 64 + lane];
            accx0 += v0 * w0.x; accy0 += v0 * w0.y;
            accx1 += v1 * w1.x; accy1 += v1 * w1.y;
            accx0 += v2 * w2.x; accy0 += v2 * w2.y;
            accx1 += v3 * w3.x; accy1 += v3 * w3.y;
        }
    }
    float2 bb = ((const float2*)b)[lane];
    ((float2*)out)[(size_t)row * 64 + lane] =
        make_float2(accx0 + accx1 + bb.x, accy0 + accy1 + bb.y);
}

// ---------- tier-3 fallback (atomic path) ----------

__global__ void init_bias_kernel(float* __restrict__ out, const float* __restrict__ b, int total4) {
    const float4* b4 = (const float4*)b;
    float4* out4 = (float4*)out;
    int stride = gridDim.x * blockDim.x;
    for (int j = blockIdx.x * blockDim.x + threadIdx.x; j < total4; j += stride)
        out4[j] = b4[j & 31];
}

__global__ void scatter_atomic_kernel(const float* __restrict__ vals, const int* __restrict__ rows,
                                      const int* __restrict__ cols, const float* __restrict__ W,
                                      float* __restrict__ out, int nnz) {
    long long idx = (long long)blockIdx.x * blockDim.x + threadIdx.x;
    int i = (int)(idx >> 5);
    int c = (int)(idx & 31);
    if (i >= nnz) return;
    int row = rows[i], col = cols[i];
    float v = vals[i];
    float4 w = ((const float4*)W)[col * 32 + c];
    float* o = out + (size_t)row * UNITS + (c << 2);
    atomicAdd(o + 0, v * w.x);
    atomicAdd(o + 1, v * w.y);
    atomicAdd(o + 2, v * w.z);
    atomicAdd(o + 3, v * w.w);
}

extern "C" void kernel_launch(void* const* d_in, const int* in_sizes, int n_in,
                              void* d_out, int out_size, void* d_ws, size_t ws_size,
                              hipStream_t stream) {
    const float* vals = (const float*)d_in[0];
    const int*   rows = (const int*)d_in[1];
    const int*   cols = (const int*)d_in[2];
    const float* W    = (const float*)d_in[3];
    const float* b    = (const float*)d_in[4];
    float* out = (float*)d_out;

    const int nnz = in_sizes[0];
    const int NW  = in_sizes[3];            // 8192*128
    const int NR  = out_size / UNITS;
    const int NS  = NR + 1;
    const int NB  = (NS + SCAN_BLK - 1) / SCAN_BLK;
    const int nbc = (NR + 255) >> 8;        // 256-row coarse buckets

    auto align = [](size_t x) { return (x + 255) & ~(size_t)255; };

    // fast-path layout
    size_t off_ccur    = 0;
    size_t off_scnt    = align(off_ccur + (size_t)nbc * 4);
    size_t off_spill   = align(off_scnt + 4);
    size_t off_wh      = align(off_spill + (size_t)SPILL_CAP * 8);
    size_t off_sortedA = align(off_wh + (size_t)NW * 2);
    size_t needed_full = off_sortedA + (size_t)nbc * BCAP * 8;   // ~23.5 MB

    // tier-2 layout (R2 pipeline)
    size_t t2_counts   = 0;
    size_t t2_tmp      = align(t2_counts + (size_t)NR * 4);
    size_t t2_bsums    = align(t2_tmp    + (size_t)NS * 4);
    size_t t2_rowstart = align(t2_bsums  + (size_t)NB * 4);
    size_t t2_cursor   = align(t2_rowstart + (size_t)NS * 4);
    size_t t2_sorted   = align(t2_cursor + (size_t)NR * 4);
    size_t needed_r2   = t2_sorted + (size_t)nnz * 8;            // ~18 MB

    char* ws = (char*)d_ws;

    if (ws_size >= needed_full) {
        int*     ccur      = (int*)(ws + off_ccur);
        int*     spill_cnt = (int*)(ws + off_scnt);
        float2*  spill     = (float2*)(ws + off_spill);
        __half2* Wh        = (__half2*)(ws + off_wh);
        float2*  sortedA   = (float2*)(ws + off_sortedA);

        setup_kernel<<<512, 256, 0, stream>>>(W, Wh, ccur, spill_cnt, nbc, NW / 2);
        {
            int grid = (nnz + CH - 1) / CH;
            partition_kernel<<<grid, 256, 0, stream>>>(vals, rows, cols, ccur, sortedA,
                                                       spill_cnt, spill, nnz, nbc);
        }
        fused_sort_compute_kernel<<<nbc, 1024, 0, stream>>>(sortedA, ccur, Wh, b, out,
                                                            spill_cnt, spill, NR);
    } else if (ws_size >= needed_r2) {
        int*    counts    = (int*)(ws + t2_counts);
        int*    tmp       = (int*)(ws + t2_tmp);
        int*    bsums     = (int*)(ws + t2_bsums);
        int*    row_start = (int*)(ws + t2_rowstart);
        int*    cursor    = (int*)(ws + t2_cursor);
        float2* sorted    = (float2*)(ws + t2_sorted);

        hipMemsetAsync(counts, 0, (size_t)NR * 4, stream);
        {
            int block = 256, grid = (nnz + block - 1) / block;
            hist_kernel<<<grid, block, 0, stream>>>(rows, counts, nnz);
        }
        scan1_kernel<<<NB, SCAN_BLK, 0, stream>>>(counts, tmp, bsums, NR, NS);
        scan2_kernel<<<1, 64, 0, stream>>>(bsums, NB);
        {
            int block = 256, grid = (NS + block - 1) / block;
            scan3_kernel<<<grid, block, 0, stream>>>(tmp, bsums, row_start, cursor, NR, NS);
        }
        {
            int block = 256, grid = (nnz + block - 1) / block;
            scatter_sort_kernel<<<grid, block, 0, stream>>>(vals, rows, cols, cursor, sorted, nnz);
        }
        {
            int grid = (NR + 3) / 4;
            compute_kernel<<<grid, 256, 0, stream>>>(sorted, row_start, W, b, out, NR);
        }
    } else {
        int total4 = out_size / 4;
        int block = 256;
        int grid = (total4 + block - 1) / block;
        init_bias_kernel<<<grid, block, 0, stream>>>(out, b, total4);
        long long total_threads = (long long)nnz * 32;
        long long g2 = (total_threads + block - 1) / block;
        scatter_atomic_kernel<<<(int)g2, block, 0, stream>>>(vals, rows, cols, W, out, nnz);
    }
}